// Round 10
// baseline (49.543 us; speedup 1.0000x reference)
//
#include <hip/hip_runtime.h>

#define NNODE   18
#define ADJ_B   1296                    // bytes per batch matrix
#define ADJ_F   324                     // floats per batch matrix
#define NF_B    72                      // bytes per batch node-features
#define TILE    16                      // batches per tile: 16 quads = FULL 64-lane packing
#define ADJ_T   (TILE * ADJ_B)          // 20,736
#define NF_T    (TILE * NF_B)           // 1,152
#define BUF_B   (ADJ_T + NF_T)          // 21,888 ; x2 = 43,776 -> exactly 3 blocks/CU
#define SOPS    23                      // fixed DMA ops per stage: 20+1 adj, 1+1 nf
#define GRID    768                     // persistent: 3 one-wave blocks per CU

__device__ __forceinline__ void gload_lds16(const void* g, void* l) {
    __builtin_amdgcn_global_load_lds((const __attribute__((address_space(1))) void*)g,
                                     (__attribute__((address_space(3))) void*)l, 16, 0, 0);
}

// quad_perm broadcast of lane P within each 4-lane group (bit15=1 -> quad mode)
#define QB(v, P) __int_as_float(__builtin_amdgcn_ds_swizzle(__float_as_int(v), 0x8000 + 0x55 * (P)))
#define GATHER18(dst, src)                                                      \
    dst[0]=QB(src[0],0);  dst[1]=QB(src[0],1);  dst[2]=QB(src[0],2);  dst[3]=QB(src[0],3);   \
    dst[4]=QB(src[1],0);  dst[5]=QB(src[1],1);  dst[6]=QB(src[1],2);  dst[7]=QB(src[1],3);   \
    dst[8]=QB(src[2],0);  dst[9]=QB(src[2],1);  dst[10]=QB(src[2],2); dst[11]=QB(src[2],3);  \
    dst[12]=QB(src[3],0); dst[13]=QB(src[3],1); dst[14]=QB(src[3],2); dst[15]=QB(src[3],3);  \
    dst[16]=QB(src[4],0); dst[17]=QB(src[4],1);

__global__ __launch_bounds__(64, 1) void gcnn_fused(
    const float* __restrict__ nf, const float* __restrict__ adj,
    const float* __restrict__ proj_w, const float* __restrict__ proj_b,
    const float* __restrict__ w1, const float* __restrict__ b1,
    const float* __restrict__ w2, const float* __restrict__ b2,
    const float* __restrict__ w3, const float* __restrict__ b3,
    float* __restrict__ out, int B)
{
    __shared__ __align__(16) char smem[2 * BUF_B];  // double buffer, LINEAR (DMA dest)
    const int lane = threadIdx.x;                   // block = 1 wave: no barriers anywhere
    const int p    = lane & 3;                      // quad lane: owns rows r ≡ p (mod 4)
    const int Q    = lane >> 2;                     // quad = batch within tile (0..15)
    const int NT   = B / TILE;                      // 8192 exactly (131072 = 8192*16)

    // Fixed 23 DMA ops per stage; ALL addresses in-bounds by construction (t < NT).
    auto stage = [&](int t, char* buf) {
        const char* ab = (const char*)adj + (size_t)t * ADJ_T + lane * 16;
        #pragma unroll
        for (int c = 0; c < 20; ++c)
            gload_lds16(ab + c * 1024, buf + c * 1024);
        if (lane < 16)                              // adj tail 256 B (always 16 lanes -> issues)
            gload_lds16(ab + 20480, buf + 20480);
        const char* nb = (const char*)nf + (size_t)t * NF_T + lane * 16;
        gload_lds16(nb, buf + ADJ_T);               // nf 1024 B
        if (lane < 8)                               // nf tail 128 B
            gload_lds16(nb + 1024, buf + ADJ_T + 1024);
    };

    auto compute = [&](int t, const char* buf) {
        const int b = t * TILE + Q;                 // always < B (exact division)

        // x from LDS: quad-uniform addresses -> broadcast reads
        float x[NNODE];
        const float2* __restrict__ xp = (const float2*)(buf + ADJ_T + Q * NF_B);
        #pragma unroll
        for (int j = 0; j < 9; ++j) { float2 v = xp[j]; x[2*j] = v.x; x[2*j+1] = v.y; }

        // LDS -> registers: lane p reads rows 4u+p of its quad's batch
        float a[5][NNODE];
        const float* __restrict__ my = (const float*)buf + Q * ADJ_F;
        #pragma unroll
        for (int u = 0; u < 5; ++u) {
            int r  = 4 * u + p;
            int ro = r < NNODE ? r : NNODE - 1;     // lanes p>=2,u=4: clamped dummy (unused)
            const float2* __restrict__ rp = (const float2*)(my + ro * NNODE);
            #pragma unroll
            for (int j = 0; j < 9; ++j) { float2 v = rp[j]; a[u][2*j] = v.x; a[u][2*j+1] = v.y; }
        }
        const float pw = proj_w[0], pb = proj_b[0];

        // Layer 1: h = relu(pw*(A x)/deg + pb), deg = row-sum (A·1 = deg, proj is 1x1)
        float inv[5], h[5];
        #pragma unroll
        for (int u = 0; u < 5; ++u) {
            float d = 0.f, s = 0.f;
            #pragma unroll
            for (int m = 0; m < NNODE; ++m) { d += a[u][m]; s += a[u][m] * x[m]; }
            inv[u] = 1.0f / d;
            h[u]   = fmaxf(0.f, pw * s * inv[u] + pb);
        }
        float hf[NNODE];
        GATHER18(hf, h)

        // Layer 2 from register-resident A; NaN-scrub per reference
        float y[5];
        #pragma unroll
        for (int u = 0; u < 5; ++u) {
            float s = 0.f;
            #pragma unroll
            for (int m = 0; m < NNODE; ++m) s += a[u][m] * hf[m];
            float v = fmaxf(0.f, pw * s * inv[u] + pb);
            y[u] = (v != v) ? 0.f : v;
        }
        float yf[NNODE];
        GATHER18(yf, y)

        // MLP head (quad-redundant; weights lane-uniform -> scalar/broadcast loads)
        float z1[10];
        #pragma unroll
        for (int k = 0; k < 10; ++k) {
            float s = b1[k];
            #pragma unroll
            for (int j = 0; j < NNODE; ++j) s += w1[k*NNODE + j] * yf[j];
            z1[k] = fmaxf(0.f, s);
        }
        float z2[8];
        #pragma unroll
        for (int k = 0; k < 8; ++k) {
            float s = b2[k];
            #pragma unroll
            for (int j = 0; j < 10; ++j) s += w2[k*10 + j] * z1[j];
            z2[k] = fmaxf(0.f, s);
        }
        float o0 = b3[0], o1 = b3[1];
        #pragma unroll
        for (int j = 0; j < 8; ++j) { o0 += w3[j] * z2[j]; o1 += w3[8 + j] * z2[j]; }

        if (p == 0)
            *(float2*)(out + (size_t)b * 2) = make_float2(o0, o1);
    };

    // ---- Persistent per-wave pipeline: outstanding DMA never drops below one tile ----
    char* cur = smem;
    char* nxt = smem + BUF_B;
    int t = blockIdx.x;
    stage(t, cur);                                  // prologue: 23 ops in flight
    for (; t < NT; t += GRID) {
        const int tn = t + GRID;
        if (tn < NT) {
            stage(tn, nxt);                         // +23 ops (newest)
            asm volatile("s_waitcnt vmcnt(23)" ::: "memory");  // tile t resident; t+1 in flight
        } else {
            asm volatile("s_waitcnt vmcnt(0)" ::: "memory");   // final tile
        }
        compute(t, cur);
        char* tmp = cur; cur = nxt; nxt = tmp;
    }
}

extern "C" void kernel_launch(void* const* d_in, const int* in_sizes, int n_in,
                              void* d_out, int out_size, void* d_ws, size_t ws_size,
                              hipStream_t stream) {
    const float* nf  = (const float*)d_in[0];
    const float* adj = (const float*)d_in[1];
    const float* pw  = (const float*)d_in[2];
    const float* pb  = (const float*)d_in[3];
    const float* w1  = (const float*)d_in[4];
    const float* b1  = (const float*)d_in[5];
    const float* w2  = (const float*)d_in[6];
    const float* b2  = (const float*)d_in[7];
    const float* w3  = (const float*)d_in[8];
    const float* b3  = (const float*)d_in[9];
    float* out = (float*)d_out;

    const int B = in_sizes[0] / NNODE;              // 131072

    gcnn_fused<<<GRID, 64, 0, stream>>>(nf, adj, pw, pb, w1, b1, w2, b2, w3, b3, out, B);
}

// Round 11
// 35.662 us; speedup vs baseline: 1.3893x; 1.3893x over previous
//
#include <hip/hip_runtime.h>

#define NNODE  18
#define ADJ_B  1296                     // bytes per batch matrix
#define ADJ_F  324                      // floats per batch matrix
#define TILE   16                       // batches per 1-wave block: 16 quads = FULL packing
#define TILE_B (TILE * ADJ_B)           // 20,736 B = exactly 1296 float4 -> 7 blocks/CU

// quad_perm broadcast of lane P within each 4-lane group (bit15=1 -> quad mode)
#define QB(v, P) __int_as_float(__builtin_amdgcn_ds_swizzle(__float_as_int(v), 0x8000 + 0x55 * (P)))
#define GATHER18(dst, src)                                                      \
    dst[0]=QB(src[0],0);  dst[1]=QB(src[0],1);  dst[2]=QB(src[0],2);  dst[3]=QB(src[0],3);   \
    dst[4]=QB(src[1],0);  dst[5]=QB(src[1],1);  dst[6]=QB(src[1],2);  dst[7]=QB(src[1],3);   \
    dst[8]=QB(src[2],0);  dst[9]=QB(src[2],1);  dst[10]=QB(src[2],2); dst[11]=QB(src[2],3);  \
    dst[12]=QB(src[3],0); dst[13]=QB(src[3],1); dst[14]=QB(src[3],2); dst[15]=QB(src[3],3);  \
    dst[16]=QB(src[4],0); dst[17]=QB(src[4],1);

__global__ __launch_bounds__(64, 2) void gcnn_fused(
    const float* __restrict__ nf, const float* __restrict__ adj,
    const float* __restrict__ proj_w, const float* __restrict__ proj_b,
    const float* __restrict__ w1, const float* __restrict__ b1,
    const float* __restrict__ w2, const float* __restrict__ b2,
    const float* __restrict__ w3, const float* __restrict__ b3,
    float* __restrict__ out, int B)
{
    __shared__ __align__(16) float smem[TILE_B / 4];   // 20,736 B -> 7 blocks/CU
    const int lane = threadIdx.x;                      // block = 1 wave
    const int p    = lane & 3;                         // quad lane: owns rows r ≡ p (mod 4)
    const int Q    = lane >> 2;                        // quad = batch within tile (0..15)
    const int b    = blockIdx.x * TILE + Q;            // B = 8192*16: never OOB

    // ---- Stage: per-lane contiguous float4 loads (identical pattern to the 6.3TB/s
    //      copy ubench) -> registers (static indices) -> ds_write_b128 ----
    const float4* __restrict__ gsrc =
        (const float4*)((const char*)adj + (size_t)blockIdx.x * TILE_B);
    float4 v[20];
    #pragma unroll
    for (int k = 0; k < 20; ++k) v[k] = gsrc[lane + 64 * k];   // 1280 float4
    float4 vt;
    if (lane < 16) vt = gsrc[1280 + lane];                     // tail 16 float4

    // x loads: quad-uniform addresses (broadcast-friendly); retired by the same drain
    float x[NNODE];
    const float2* __restrict__ xp = (const float2*)(nf + (size_t)b * NNODE);
    #pragma unroll
    for (int j = 0; j < 9; ++j) { float2 vx = xp[j]; x[2*j] = vx.x; x[2*j+1] = vx.y; }

    float4* __restrict__ sp = (float4*)smem;
    #pragma unroll
    for (int k = 0; k < 20; ++k) sp[lane + 64 * k] = v[k];     // contiguous b128 writes
    if (lane < 16) sp[1280 + lane] = vt;

    __syncthreads();   // 1-wave block: lgkmcnt(0)+vmcnt(0) drain + trivial barrier

    // ---- Compute (proven R9 structure): lane p reads rows 4u+p of its quad's batch ----
    float a[5][NNODE];
    const float* __restrict__ my = smem + Q * ADJ_F;
    #pragma unroll
    for (int u = 0; u < 5; ++u) {
        int r  = 4 * u + p;
        int ro = r < NNODE ? r : NNODE - 1;            // lanes p>=2,u=4: clamped dummy (unused)
        const float2* __restrict__ rp = (const float2*)(my + ro * NNODE);
        #pragma unroll
        for (int j = 0; j < 9; ++j) { float2 t = rp[j]; a[u][2*j] = t.x; a[u][2*j+1] = t.y; }
    }
    const float pw = proj_w[0], pb = proj_b[0];

    // Layer 1: h = relu(pw*(A x)/deg + pb), deg = row-sum (A·1 = deg, proj is 1x1)
    float inv[5], h[5];
    #pragma unroll
    for (int u = 0; u < 5; ++u) {
        float d = 0.f, s = 0.f;
        #pragma unroll
        for (int m = 0; m < NNODE; ++m) { d += a[u][m]; s += a[u][m] * x[m]; }
        inv[u] = 1.0f / d;
        h[u]   = fmaxf(0.f, pw * s * inv[u] + pb);
    }
    float hf[NNODE];
    GATHER18(hf, h)

    // Layer 2 from register-resident A; NaN-scrub per reference
    float y[5];
    #pragma unroll
    for (int u = 0; u < 5; ++u) {
        float s = 0.f;
        #pragma unroll
        for (int m = 0; m < NNODE; ++m) s += a[u][m] * hf[m];
        float vv = fmaxf(0.f, pw * s * inv[u] + pb);
        y[u] = (vv != vv) ? 0.f : vv;
    }
    float yf[NNODE];
    GATHER18(yf, y)

    // MLP head (quad-redundant; weights lane-uniform -> scalar/broadcast loads)
    float z1[10];
    #pragma unroll
    for (int k = 0; k < 10; ++k) {
        float s = b1[k];
        #pragma unroll
        for (int j = 0; j < NNODE; ++j) s += w1[k*NNODE + j] * yf[j];
        z1[k] = fmaxf(0.f, s);
    }
    float z2[8];
    #pragma unroll
    for (int k = 0; k < 8; ++k) {
        float s = b2[k];
        #pragma unroll
        for (int j = 0; j < 10; ++j) s += w2[k*10 + j] * z1[j];
        z2[k] = fmaxf(0.f, s);
    }
    float o0 = b3[0], o1 = b3[1];
    #pragma unroll
    for (int j = 0; j < 8; ++j) { o0 += w3[j] * z2[j]; o1 += w3[8 + j] * z2[j]; }

    if (p == 0)
        *(float2*)(out + (size_t)b * 2) = make_float2(o0, o1);   // 16x float2, contiguous
}

extern "C" void kernel_launch(void* const* d_in, const int* in_sizes, int n_in,
                              void* d_out, int out_size, void* d_ws, size_t ws_size,
                              hipStream_t stream) {
    const float* nf  = (const float*)d_in[0];
    const float* adj = (const float*)d_in[1];
    const float* pw  = (const float*)d_in[2];
    const float* pb  = (const float*)d_in[3];
    const float* w1  = (const float*)d_in[4];
    const float* b1  = (const float*)d_in[5];
    const float* w2  = (const float*)d_in[6];
    const float* b2  = (const float*)d_in[7];
    const float* w3  = (const float*)d_in[8];
    const float* b3  = (const float*)d_in[9];
    float* out = (float*)d_out;

    const int B = in_sizes[0] / NNODE;                    // 131072
    const int grid = (B + TILE - 1) / TILE;               // 8192 one-wave blocks

    gcnn_fused<<<grid, 64, 0, stream>>>(nf, adj, pw, pb, w1, b1, w2, b2, w3, b3, out, B);
}